// Round 1
// 568.174 us; speedup vs baseline: 1.1321x; 1.1321x over previous
//
#include <hip/hip_runtime.h>
#include <hip/hip_bf16.h>
#include <math.h>

#define T_ 12
#define E_ 8192
#define H_ 256
#define V_ 800
#define B_ 256
#define NB_ 8
#define M_ (T_*E_)
#define TM 16            // message rows per k_step block
#define HP (H_ + 8)      // bf16 LDS row pad

typedef __attribute__((ext_vector_type(8))) short bf16x8;
typedef __attribute__((ext_vector_type(4))) float f32x4;

#define LOG2E_ 1.44269504088896f

// fast native transcendentals (v_exp_f32 = 2^x, v_rcp_f32)
__device__ __forceinline__ float fexp2_(float x) { return __builtin_amdgcn_exp2f(x); }
__device__ __forceinline__ float frcp_(float x)  { return __builtin_amdgcn_rcpf(x); }
__device__ __forceinline__ float fsig(float x) {
    return frcp_(1.0f + fexp2_(-LOG2E_ * x));
}
__device__ __forceinline__ float ftanh(float x) {
    // tanh(x) = 1 - 2/(exp(2x)+1); large |x| saturates correctly via inf/0
    return 1.0f - 2.0f * frcp_(fexp2_(2.0f * LOG2E_ * x) + 1.0f);
}

// RNE f32 -> bf16 bits
__device__ __forceinline__ short f2bf(float x) {
    unsigned u = __float_as_uint(x);
    unsigned r = (u + 0x7fffu + ((u >> 16) & 1u)) >> 16;
    return (short)r;
}
__device__ __forceinline__ float bf2f(unsigned short s) {
    return __uint_as_float(((unsigned)s) << 16);
}
// packed word: lo16 -> float via <<16, hi16 -> float via mask
__device__ __forceinline__ float hu_h(unsigned v) { return __uint_as_float(v << 16); }
__device__ __forceinline__ float hu_u(unsigned v) { return __uint_as_float(v & 0xffff0000u); }
__device__ __forceinline__ unsigned pack2(float a, float b) {
    return (unsigned)(unsigned short)f2bf(a) | ((unsigned)(unsigned short)f2bf(b) << 16);
}

// Weight prep (+ slot-0 init folded into block 768).
// Wzt[n][k] = Wz[256+k][n], Wht[n][k] = Wh[256+k][n], Urt[n][k] = Ur[k][n], bf16.
__global__ __launch_bounds__(256) void k_wconv(
    const float* __restrict__ Wz, const float* __restrict__ Wh, const float* __restrict__ Ur,
    short* __restrict__ Wzt, short* __restrict__ Wht, short* __restrict__ Urt,
    float* __restrict__ h, unsigned* __restrict__ hu)
{
    if (blockIdx.x == 768) {            // zero padding row (slot 0) of h and hu
        h[threadIdx.x] = 0.0f;
        hu[threadIdx.x] = 0u;
        return;
    }
    int tid = blockIdx.x * 256 + threadIdx.x;
    int w = tid >> 16;
    int idx = tid & 65535;
    int n = idx >> 8, k = idx & 255;
    if (w == 0)      Wzt[idx] = f2bf(Wz[(size_t)(256 + k) * H_ + n]);
    else if (w == 1) Wht[idx] = f2bf(Wh[(size_t)(256 + k) * H_ + n]);
    else             Urt[idx] = f2bf(Ur[(size_t)k * H_ + n]);
}

// Batched prelude: eW*[v] = emb[v] @ Btop + bias  (blockIdx.z selects table)
__global__ __launch_bounds__(256) void gemm_pre(
    const float* __restrict__ emb,
    const float* __restrict__ Wr, const float* __restrict__ Wz,
    const float* __restrict__ Wh, const float* __restrict__ Wo,
    const float* __restrict__ bur, const float* __restrict__ bz,
    const float* __restrict__ bh, const float* __restrict__ bo,
    float* __restrict__ eWr, float* __restrict__ eWz,
    float* __restrict__ eWh, float* __restrict__ eWo)
{
    const float* Bm; const float* bias; float* C;
    switch (blockIdx.z) {
        case 0: Bm = Wr; bias = bur; C = eWr; break;
        case 1: Bm = Wz; bias = bz;  C = eWz; break;
        case 2: Bm = Wh; bias = bh;  C = eWh; break;
        default: Bm = Wo; bias = bo; C = eWo; break;
    }
    __shared__ float As[16][64];
    __shared__ float Bs[16][64];
    const int tid = threadIdx.x;
    const int bm = blockIdx.x * 64;
    const int bn = blockIdx.y * 64;
    const int a_m = tid & 63;
    const int a_k = (tid >> 6) << 2;
    const int b_k = tid >> 4;
    const int b_n = (tid & 15) << 2;
    const int tx = tid & 15, ty = tid >> 4;

    float acc[4][4] = {};
    const bool a_ok = (bm + a_m) < V_;
    const float* Ap = emb + (size_t)(bm + a_m) * H_ + a_k;
    const float* Bp = Bm + (size_t)b_k * H_ + bn + b_n;

    for (int k0 = 0; k0 < H_; k0 += 16) {
        float4 av = a_ok ? *(const float4*)(Ap + k0) : make_float4(0.f, 0.f, 0.f, 0.f);
        float4 bv = *(const float4*)(Bp + (size_t)k0 * H_);
        __syncthreads();
        As[a_k + 0][a_m] = av.x;
        As[a_k + 1][a_m] = av.y;
        As[a_k + 2][a_m] = av.z;
        As[a_k + 3][a_m] = av.w;
        *(float4*)&Bs[b_k][b_n] = bv;
        __syncthreads();
#pragma unroll
        for (int k = 0; k < 16; ++k) {
            const float4 a4 = *(const float4*)&As[k][ty << 2];
            const float4 b4 = *(const float4*)&Bs[k][tx << 2];
            const float ar[4] = {a4.x, a4.y, a4.z, a4.w};
            const float br[4] = {b4.x, b4.y, b4.z, b4.w};
#pragma unroll
            for (int i = 0; i < 4; ++i)
#pragma unroll
                for (int j = 0; j < 4; ++j)
                    acc[i][j] = fmaf(ar[i], br[j], acc[i][j]);
        }
    }

    const int col = bn + (tx << 2);
#pragma unroll
    for (int i = 0; i < 4; ++i) {
        const int row = bm + (ty << 2) + i;
        if (row >= V_) break;
        *(float4*)(C + (size_t)row * H_ + col) =
            make_float4(acc[i][0] + bias[col], acc[i][1] + bias[col + 1],
                        acc[i][2] + bias[col + 2], acc[i][3] + bias[col + 3]);
    }
}

// Pack epilogue tables: eWzh = {lo16: bf16(eWz), hi16: bf16(eWh)}
__global__ __launch_bounds__(256) void k_pack(
    const float* __restrict__ eWz, const float* __restrict__ eWh,
    unsigned* __restrict__ eWzh)
{
    const int i = blockIdx.x * 256 + threadIdx.x;   // V_*H_ = 204800 = 800*256
    eWzh[i] = pack2(eWz[i], eWh[i]);
}

// Fused step, 512 threads (8 waves), ~25.3 KB LDS -> 4 blocks/CU (32 waves/CU).
// Each wave owns a 32-col strip and computes BOTH Z and H accums for it, so the
// epilogue is in-register (no LDS exchange). Tables eWr/eWzh include biases.
__global__ __launch_bounds__(512, 8) void k_step(
    int t,
    const int* __restrict__ x_ids, const int* __restrict__ nei_idx,
    float* __restrict__ h, unsigned* __restrict__ hu,
    const float* __restrict__ eWr, const unsigned* __restrict__ eWzh,
    const short* __restrict__ Wzt, const short* __restrict__ Wht,
    const short* __restrict__ Urt,
    int do_ur)
{
    __shared__ int   idx[TM][NB_];
    __shared__ int   xw[TM];
    __shared__ short shB[TM][HP];   // sumh bf16 (A-frag + epilogue linear term)
    __shared__ short sgB[TM][HP];   // sumg bf16 (A-frag)
    __shared__ short hB[TM][HP];    // h_t bf16 (A-frag Ur + hu pack)

    const int tid = threadIdx.x;
    const int e0 = blockIdx.x * TM;

    if (tid < TM * NB_) {
        int r = tid >> 3, j = tid & 7;
        idx[r][j] = nei_idx[((size_t)t * E_ + e0 + r) * NB_ + j];
    }
    if (tid < TM) xw[tid] = x_ids[t * E_ + e0 + tid];
    __syncthreads();

    // ---- gather: thread = (col-pair, row-group); uint2 loads, 8 in flight ----
    {
        const int c0 = (tid & 127) * 2;
        const int rbase = (tid >> 7) * 4;
        if (t == 0) {
            // all neighbor slots are the zero pad at t=0
#pragma unroll
            for (int rr = 0; rr < 4; ++rr) {
                *(unsigned*)&shB[rbase + rr][c0] = 0u;
                *(unsigned*)&sgB[rbase + rr][c0] = 0u;
            }
        } else {
            for (int rr = 0; rr < 4; ++rr) {
                const int r = rbase + rr;
                uint2 v[NB_];
#pragma unroll
                for (int j = 0; j < NB_; ++j)
                    v[j] = *(const uint2*)(hu + (size_t)idx[r][j] * H_ + c0);
                const float2 r1 = *(const float2*)(eWr + (size_t)xw[r] * H_ + c0);
                float sh0 = 0.f, sg0 = 0.f, sh1 = 0.f, sg1 = 0.f;
#pragma unroll
                for (int j = 0; j < NB_; ++j) {
                    const float h0 = hu_h(v[j].x);
                    sh0 += h0;
                    sg0 = fmaf(fsig(r1.x + hu_u(v[j].x)), h0, sg0);
                    const float h1 = hu_h(v[j].y);
                    sh1 += h1;
                    sg1 = fmaf(fsig(r1.y + hu_u(v[j].y)), h1, sg1);
                }
                *(unsigned*)&shB[r][c0] = pack2(sh0, sh1);
                *(unsigned*)&sgB[r][c0] = pack2(sg0, sg1);
            }
        }
    }
    __syncthreads();

    // ---- MFMA + in-register epilogue: wave owns 32-col strip, both Z and H ----
    const int lane = tid & 63;
    const int wave = tid >> 6;           // 0..7
    const int n0 = wave * 32;
    const int quad = lane >> 4, c = lane & 15;
    const int kq = quad * 8;

    f32x4 accZ[2], accH[2];
#pragma unroll
    for (int i = 0; i < 2; ++i) { accZ[i] = (f32x4)(0.0f); accH[i] = (f32x4)(0.0f); }

#pragma unroll
    for (int k0 = 0; k0 < H_; k0 += 32) {
        const bf16x8 a1 = *(const bf16x8*)&shB[c][k0 + kq];
        const bf16x8 a2 = *(const bf16x8*)&sgB[c][k0 + kq];
#pragma unroll
        for (int ni = 0; ni < 2; ++ni) {
            const size_t boff = (size_t)(n0 + ni * 16 + c) * H_ + k0 + kq;
            const bf16x8 b1 = *(const bf16x8*)(Wzt + boff);
            const bf16x8 b2 = *(const bf16x8*)(Wht + boff);
            accZ[ni] = __builtin_amdgcn_mfma_f32_16x16x32_bf16(a1, b1, accZ[ni], 0, 0, 0);
            accH[ni] = __builtin_amdgcn_mfma_f32_16x16x32_bf16(a2, b2, accH[ni], 0, 0, 0);
        }
    }

    // epilogue: h_t = (1-z)*sumh + z*pre, all in-register per C-cell
    float* h_t = h + (size_t)(1 + t * E_) * H_;
#pragma unroll
    for (int reg = 0; reg < 4; ++reg) {
        const int r = quad * 4 + reg;
        const int xr = xw[r];
#pragma unroll
        for (int ni = 0; ni < 2; ++ni) {
            const int col = n0 + ni * 16 + c;
            const unsigned zh = eWzh[(size_t)xr * H_ + col];
            const float z   = fsig(accZ[ni][reg] + hu_h(zh));
            const float pre = ftanh(accH[ni][reg] + hu_u(zh));
            const float hv = (1.0f - z) * bf2f((unsigned short)shB[r][col]) + z * pre;
            h_t[(size_t)(e0 + r) * H_ + col] = hv;
            hB[r][col] = f2bf(hv);
        }
    }

    if (!do_ur) return;
    __syncthreads();

    // ---- Ur MFMA: u = h_t @ Ur; store packed {h_bf16, u_bf16} ----
    {
        f32x4 accU[2];
        accU[0] = (f32x4)(0.0f); accU[1] = (f32x4)(0.0f);
#pragma unroll
        for (int k0 = 0; k0 < H_; k0 += 32) {
            const bf16x8 a = *(const bf16x8*)&hB[c][k0 + kq];
#pragma unroll
            for (int ni = 0; ni < 2; ++ni) {
                const bf16x8 b = *(const bf16x8*)(Urt + (size_t)(n0 + ni * 16 + c) * H_ + k0 + kq);
                accU[ni] = __builtin_amdgcn_mfma_f32_16x16x32_bf16(a, b, accU[ni], 0, 0, 0);
            }
        }
        unsigned* hu_t = hu + (size_t)(1 + t * E_) * H_;
#pragma unroll
        for (int reg = 0; reg < 4; ++reg) {
            const int r = quad * 4 + reg;
#pragma unroll
            for (int ni = 0; ni < 2; ++ni) {
                const int col = n0 + ni * 16 + c;
                const unsigned ubits = (unsigned)(unsigned short)f2bf(accU[ni][reg]);
                const unsigned hbits = (unsigned)(unsigned short)hB[r][col];
                hu_t[(size_t)(e0 + r) * H_ + col] = (ubits << 16) | hbits;
            }
        }
    }
}

// root_vecs[b] = relu(eWo[root_wid[b]] + sum_nei @ Wo_bot)   (eWo includes bo)
__global__ __launch_bounds__(256) void k_root(
    const int* __restrict__ root_wid, const int* __restrict__ root_nei,
    const float* __restrict__ h, const float* __restrict__ eWo,
    const float* __restrict__ Wo, float* __restrict__ out)
{
    const int b = blockIdx.x, d = threadIdx.x;
    __shared__ float sn[H_];
    __shared__ int idx[NB_];
    if (d < NB_) idx[d] = root_nei[b * NB_ + d];
    __syncthreads();
    float s = 0.0f;
#pragma unroll
    for (int j = 0; j < NB_; ++j) s += h[(size_t)idx[j] * H_ + d];
    sn[d] = s;
    __syncthreads();
    float acc = eWo[(size_t)root_wid[b] * H_ + d];
    for (int k = 0; k < H_; ++k)
        acc = fmaf(sn[k], Wo[(size_t)(H_ + k) * H_ + d], acc);
    out[(size_t)b * H_ + d] = fmaxf(acc, 0.0f);
}

extern "C" void kernel_launch(void* const* d_in, const int* in_sizes, int n_in,
                              void* d_out, int out_size, void* d_ws, size_t ws_size,
                              hipStream_t stream)
{
    const int*   x_ids    = (const int*)d_in[0];
    const int*   nei_idx  = (const int*)d_in[1];
    const int*   root_wid = (const int*)d_in[2];
    const int*   root_nei = (const int*)d_in[3];
    const float* emb      = (const float*)d_in[4];
    const float* Wz       = (const float*)d_in[5];
    const float* bz       = (const float*)d_in[6];
    const float* Wr       = (const float*)d_in[7];
    const float* Ur       = (const float*)d_in[8];
    const float* bur      = (const float*)d_in[9];
    const float* Wh       = (const float*)d_in[10];
    const float* bh       = (const float*)d_in[11];
    const float* Wo       = (const float*)d_in[12];
    const float* bo       = (const float*)d_in[13];

    float* h        = (float*)d_out;                      // [(1+M), H]
    float* root_out = h + (size_t)(1 + M_) * H_;          // [B, H]

    unsigned* hu = (unsigned*)d_ws;                       // [(1+M), H] packed {h,u} bf16
    float* eWr  = (float*)(hu + (size_t)(1 + M_) * H_);   // [V, H] emb@Wr + bur
    float* eWz  = eWr  + (size_t)V_ * H_;                 // [V, H] emb@Wz_top + bz
    float* eWh  = eWz  + (size_t)V_ * H_;                 // [V, H] emb@Wh_top + bh
    float* eWo  = eWh  + (size_t)V_ * H_;                 // [V, H] emb@Wo_top + bo
    short* Wzt  = (short*)(eWo + (size_t)V_ * H_);        // [256,256] bf16 transposed
    short* Wht  = Wzt + 65536;
    short* Urt  = Wht + 65536;
    unsigned* eWzh = (unsigned*)(Urt + 65536);            // [V, H] packed {bf16(eWz), bf16(eWh)}

    k_wconv<<<dim3(769), dim3(256), 0, stream>>>(Wz, Wh, Ur, Wzt, Wht, Urt, h, hu);
    gemm_pre<<<dim3((V_ + 63) / 64, 4, 4), dim3(256), 0, stream>>>(
        emb, Wr, Wz, Wh, Wo, bur, bz, bh, bo, eWr, eWz, eWh, eWo);
    k_pack<<<dim3(V_ * H_ / 256), dim3(256), 0, stream>>>(eWz, eWh, eWzh);

    for (int t = 0; t < T_; ++t) {
        k_step<<<dim3(E_ / TM), dim3(512), 0, stream>>>(
            t, x_ids, nei_idx, h, hu, eWr, eWzh, Wzt, Wht, Urt,
            (t < T_ - 1) ? 1 : 0);
    }

    k_root<<<dim3(B_), dim3(256), 0, stream>>>(root_wid, root_nei, h, eWo, Wo, root_out);
}

// Round 2
// 552.252 us; speedup vs baseline: 1.1647x; 1.0288x over previous
//
#include <hip/hip_runtime.h>
#include <hip/hip_bf16.h>
#include <math.h>

#define T_ 12
#define E_ 8192
#define H_ 256
#define V_ 800
#define B_ 256
#define NB_ 8
#define M_ (T_*E_)
#define TM 16            // message rows per k_step block
#define HP (H_ + 8)      // bf16 LDS row pad

typedef __attribute__((ext_vector_type(8))) short bf16x8;
typedef __attribute__((ext_vector_type(4))) float f32x4;

#define LOG2E_ 1.44269504088896f

// fast native transcendentals (v_exp_f32 = 2^x, v_rcp_f32)
__device__ __forceinline__ float fexp2_(float x) { return __builtin_amdgcn_exp2f(x); }
__device__ __forceinline__ float frcp_(float x)  { return __builtin_amdgcn_rcpf(x); }
__device__ __forceinline__ float fsig(float x) {
    return frcp_(1.0f + fexp2_(-LOG2E_ * x));
}
__device__ __forceinline__ float ftanh(float x) {
    // tanh(x) = 1 - 2/(exp(2x)+1); large |x| saturates correctly via inf/0
    return 1.0f - 2.0f * frcp_(fexp2_(2.0f * LOG2E_ * x) + 1.0f);
}

// RNE f32 -> bf16 bits
__device__ __forceinline__ short f2bf(float x) {
    unsigned u = __float_as_uint(x);
    unsigned r = (u + 0x7fffu + ((u >> 16) & 1u)) >> 16;
    return (short)r;
}
__device__ __forceinline__ float bf2f(unsigned short s) {
    return __uint_as_float(((unsigned)s) << 16);
}
// packed word: lo16 -> float via <<16, hi16 -> float via mask
__device__ __forceinline__ float hu_h(unsigned v) { return __uint_as_float(v << 16); }
__device__ __forceinline__ float hu_u(unsigned v) { return __uint_as_float(v & 0xffff0000u); }
__device__ __forceinline__ unsigned pack2(float a, float b) {
    return (unsigned)(unsigned short)f2bf(a) | ((unsigned)(unsigned short)f2bf(b) << 16);
}

// Weight prep (+ slot-0 init folded into block 768).
// Wzt[n][k] = Wz[256+k][n], Wht[n][k] = Wh[256+k][n], Urt[n][k] = Ur[k][n], bf16.
__global__ __launch_bounds__(256) void k_wconv(
    const float* __restrict__ Wz, const float* __restrict__ Wh, const float* __restrict__ Ur,
    short* __restrict__ Wzt, short* __restrict__ Wht, short* __restrict__ Urt,
    float* __restrict__ h, unsigned* __restrict__ hu)
{
    if (blockIdx.x == 768) {            // zero padding row (slot 0) of h and hu
        h[threadIdx.x] = 0.0f;
        hu[threadIdx.x] = 0u;
        return;
    }
    int tid = blockIdx.x * 256 + threadIdx.x;
    int w = tid >> 16;
    int idx = tid & 65535;
    int n = idx >> 8, k = idx & 255;
    if (w == 0)      Wzt[idx] = f2bf(Wz[(size_t)(256 + k) * H_ + n]);
    else if (w == 1) Wht[idx] = f2bf(Wh[(size_t)(256 + k) * H_ + n]);
    else             Urt[idx] = f2bf(Ur[(size_t)k * H_ + n]);
}

// Batched prelude: eW*[v] = emb[v] @ Btop + bias  (blockIdx.z selects table)
__global__ __launch_bounds__(256) void gemm_pre(
    const float* __restrict__ emb,
    const float* __restrict__ Wr, const float* __restrict__ Wz,
    const float* __restrict__ Wh, const float* __restrict__ Wo,
    const float* __restrict__ bur, const float* __restrict__ bz,
    const float* __restrict__ bh, const float* __restrict__ bo,
    float* __restrict__ eWr, float* __restrict__ eWz,
    float* __restrict__ eWh, float* __restrict__ eWo)
{
    const float* Bm; const float* bias; float* C;
    switch (blockIdx.z) {
        case 0: Bm = Wr; bias = bur; C = eWr; break;
        case 1: Bm = Wz; bias = bz;  C = eWz; break;
        case 2: Bm = Wh; bias = bh;  C = eWh; break;
        default: Bm = Wo; bias = bo; C = eWo; break;
    }
    __shared__ float As[16][64];
    __shared__ float Bs[16][64];
    const int tid = threadIdx.x;
    const int bm = blockIdx.x * 64;
    const int bn = blockIdx.y * 64;
    const int a_m = tid & 63;
    const int a_k = (tid >> 6) << 2;
    const int b_k = tid >> 4;
    const int b_n = (tid & 15) << 2;
    const int tx = tid & 15, ty = tid >> 4;

    float acc[4][4] = {};
    const bool a_ok = (bm + a_m) < V_;
    const float* Ap = emb + (size_t)(bm + a_m) * H_ + a_k;
    const float* Bp = Bm + (size_t)b_k * H_ + bn + b_n;

    for (int k0 = 0; k0 < H_; k0 += 16) {
        float4 av = a_ok ? *(const float4*)(Ap + k0) : make_float4(0.f, 0.f, 0.f, 0.f);
        float4 bv = *(const float4*)(Bp + (size_t)k0 * H_);
        __syncthreads();
        As[a_k + 0][a_m] = av.x;
        As[a_k + 1][a_m] = av.y;
        As[a_k + 2][a_m] = av.z;
        As[a_k + 3][a_m] = av.w;
        *(float4*)&Bs[b_k][b_n] = bv;
        __syncthreads();
#pragma unroll
        for (int k = 0; k < 16; ++k) {
            const float4 a4 = *(const float4*)&As[k][ty << 2];
            const float4 b4 = *(const float4*)&Bs[k][tx << 2];
            const float ar[4] = {a4.x, a4.y, a4.z, a4.w};
            const float br[4] = {b4.x, b4.y, b4.z, b4.w};
#pragma unroll
            for (int i = 0; i < 4; ++i)
#pragma unroll
                for (int j = 0; j < 4; ++j)
                    acc[i][j] = fmaf(ar[i], br[j], acc[i][j]);
        }
    }

    const int col = bn + (tx << 2);
#pragma unroll
    for (int i = 0; i < 4; ++i) {
        const int row = bm + (ty << 2) + i;
        if (row >= V_) break;
        *(float4*)(C + (size_t)row * H_ + col) =
            make_float4(acc[i][0] + bias[col], acc[i][1] + bias[col + 1],
                        acc[i][2] + bias[col + 2], acc[i][3] + bias[col + 3]);
    }
}

// Pack epilogue tables: eWzh = {lo16: bf16(eWz), hi16: bf16(eWh)}
__global__ __launch_bounds__(256) void k_pack(
    const float* __restrict__ eWz, const float* __restrict__ eWh,
    unsigned* __restrict__ eWzh)
{
    const int i = blockIdx.x * 256 + threadIdx.x;   // V_*H_ = 204800 = 800*256
    eWzh[i] = pack2(eWz[i], eWh[i]);
}

// Fused step, 512 threads (8 waves), ~25.3 KB LDS.
// Grid is 512 blocks = 2 blocks/CU (grid-limited), so only require 4 waves/EU:
// gives the register allocator 128 VGPRs (the old (512,8) bound capped at 64
// and risked scratch spills for zero occupancy benefit).
__global__ __launch_bounds__(512, 4) void k_step(
    int t,
    const int* __restrict__ x_ids, const int* __restrict__ nei_idx,
    float* __restrict__ h, unsigned* __restrict__ hu,
    const float* __restrict__ eWr, const unsigned* __restrict__ eWzh,
    const short* __restrict__ Wzt, const short* __restrict__ Wht,
    const short* __restrict__ Urt,
    int do_ur)
{
    __shared__ int   idx[TM][NB_];
    __shared__ int   xw[TM];
    __shared__ short shB[TM][HP];   // sumh bf16 (A-frag + epilogue linear term)
    __shared__ short sgB[TM][HP];   // sumg bf16 (A-frag)
    __shared__ short hB[TM][HP];    // h_t bf16 (A-frag Ur + hu pack)

    const int tid = threadIdx.x;
    const int e0 = blockIdx.x * TM;

    if (tid < TM * NB_) {
        int r = tid >> 3, j = tid & 7;
        idx[r][j] = nei_idx[((size_t)t * E_ + e0 + r) * NB_ + j];
    }
    if (tid < TM) xw[tid] = x_ids[t * E_ + e0 + tid];
    __syncthreads();

    // ---- gather: thread = (4-col group, row pair); uint4 loads, 16 in flight ----
    {
        const int c0 = (tid & 63) * 4;       // 64 col-groups x 4 cols = 256 cols
        const int ra = (tid >> 6) * 2;       // 8 row-pairs = 16 rows
        const int rb = ra + 1;
        if (t == 0) {
            // all neighbor slots are the zero pad at t=0
            *(uint2*)&shB[ra][c0] = make_uint2(0u, 0u);
            *(uint2*)&sgB[ra][c0] = make_uint2(0u, 0u);
            *(uint2*)&shB[rb][c0] = make_uint2(0u, 0u);
            *(uint2*)&sgB[rb][c0] = make_uint2(0u, 0u);
        } else {
            uint4 va[NB_], vb[NB_];
#pragma unroll
            for (int j = 0; j < NB_; ++j)
                va[j] = *(const uint4*)(hu + (size_t)idx[ra][j] * H_ + c0);
#pragma unroll
            for (int j = 0; j < NB_; ++j)
                vb[j] = *(const uint4*)(hu + (size_t)idx[rb][j] * H_ + c0);
            const float4 r1a = *(const float4*)(eWr + (size_t)xw[ra] * H_ + c0);
            const float4 r1b = *(const float4*)(eWr + (size_t)xw[rb] * H_ + c0);

            float sa0 = 0.f, sa1 = 0.f, sa2 = 0.f, sa3 = 0.f;
            float ga0 = 0.f, ga1 = 0.f, ga2 = 0.f, ga3 = 0.f;
#pragma unroll
            for (int j = 0; j < NB_; ++j) {
                const float h0 = hu_h(va[j].x); sa0 += h0;
                ga0 = fmaf(fsig(r1a.x + hu_u(va[j].x)), h0, ga0);
                const float h1 = hu_h(va[j].y); sa1 += h1;
                ga1 = fmaf(fsig(r1a.y + hu_u(va[j].y)), h1, ga1);
                const float h2 = hu_h(va[j].z); sa2 += h2;
                ga2 = fmaf(fsig(r1a.z + hu_u(va[j].z)), h2, ga2);
                const float h3 = hu_h(va[j].w); sa3 += h3;
                ga3 = fmaf(fsig(r1a.w + hu_u(va[j].w)), h3, ga3);
            }
            *(uint2*)&shB[ra][c0] = make_uint2(pack2(sa0, sa1), pack2(sa2, sa3));
            *(uint2*)&sgB[ra][c0] = make_uint2(pack2(ga0, ga1), pack2(ga2, ga3));

            float sb0 = 0.f, sb1 = 0.f, sb2 = 0.f, sb3 = 0.f;
            float gb0 = 0.f, gb1 = 0.f, gb2 = 0.f, gb3 = 0.f;
#pragma unroll
            for (int j = 0; j < NB_; ++j) {
                const float h0 = hu_h(vb[j].x); sb0 += h0;
                gb0 = fmaf(fsig(r1b.x + hu_u(vb[j].x)), h0, gb0);
                const float h1 = hu_h(vb[j].y); sb1 += h1;
                gb1 = fmaf(fsig(r1b.y + hu_u(vb[j].y)), h1, gb1);
                const float h2 = hu_h(vb[j].z); sb2 += h2;
                gb2 = fmaf(fsig(r1b.z + hu_u(vb[j].z)), h2, gb2);
                const float h3 = hu_h(vb[j].w); sb3 += h3;
                gb3 = fmaf(fsig(r1b.w + hu_u(vb[j].w)), h3, gb3);
            }
            *(uint2*)&shB[rb][c0] = make_uint2(pack2(sb0, sb1), pack2(sb2, sb3));
            *(uint2*)&sgB[rb][c0] = make_uint2(pack2(gb0, gb1), pack2(gb2, gb3));
        }
    }
    __syncthreads();

    // ---- MFMA + in-register epilogue: wave owns 32-col strip, both Z and H ----
    const int lane = tid & 63;
    const int wave = tid >> 6;           // 0..7
    const int n0 = wave * 32;
    const int quad = lane >> 4, c = lane & 15;
    const int kq = quad * 8;

    f32x4 accZ[2], accH[2];
#pragma unroll
    for (int i = 0; i < 2; ++i) { accZ[i] = (f32x4)(0.0f); accH[i] = (f32x4)(0.0f); }

#pragma unroll
    for (int k0 = 0; k0 < H_; k0 += 32) {
        const bf16x8 a1 = *(const bf16x8*)&shB[c][k0 + kq];
        const bf16x8 a2 = *(const bf16x8*)&sgB[c][k0 + kq];
#pragma unroll
        for (int ni = 0; ni < 2; ++ni) {
            const size_t boff = (size_t)(n0 + ni * 16 + c) * H_ + k0 + kq;
            const bf16x8 b1 = *(const bf16x8*)(Wzt + boff);
            const bf16x8 b2 = *(const bf16x8*)(Wht + boff);
            accZ[ni] = __builtin_amdgcn_mfma_f32_16x16x32_bf16(a1, b1, accZ[ni], 0, 0, 0);
            accH[ni] = __builtin_amdgcn_mfma_f32_16x16x32_bf16(a2, b2, accH[ni], 0, 0, 0);
        }
    }

    // epilogue: h_t = (1-z)*sumh + z*pre, all in-register per C-cell
    float* h_t = h + (size_t)(1 + t * E_) * H_;
#pragma unroll
    for (int reg = 0; reg < 4; ++reg) {
        const int r = quad * 4 + reg;
        const int xr = xw[r];
#pragma unroll
        for (int ni = 0; ni < 2; ++ni) {
            const int col = n0 + ni * 16 + c;
            const unsigned zh = eWzh[(size_t)xr * H_ + col];
            const float z   = fsig(accZ[ni][reg] + hu_h(zh));
            const float pre = ftanh(accH[ni][reg] + hu_u(zh));
            const float hv = (1.0f - z) * bf2f((unsigned short)shB[r][col]) + z * pre;
            h_t[(size_t)(e0 + r) * H_ + col] = hv;
            hB[r][col] = f2bf(hv);
        }
    }

    if (!do_ur) return;
    __syncthreads();

    // ---- Ur MFMA: u = h_t @ Ur; store packed {h_bf16, u_bf16} ----
    {
        f32x4 accU[2];
        accU[0] = (f32x4)(0.0f); accU[1] = (f32x4)(0.0f);
#pragma unroll
        for (int k0 = 0; k0 < H_; k0 += 32) {
            const bf16x8 a = *(const bf16x8*)&hB[c][k0 + kq];
#pragma unroll
            for (int ni = 0; ni < 2; ++ni) {
                const bf16x8 b = *(const bf16x8*)(Urt + (size_t)(n0 + ni * 16 + c) * H_ + k0 + kq);
                accU[ni] = __builtin_amdgcn_mfma_f32_16x16x32_bf16(a, b, accU[ni], 0, 0, 0);
            }
        }
        unsigned* hu_t = hu + (size_t)(1 + t * E_) * H_;
#pragma unroll
        for (int reg = 0; reg < 4; ++reg) {
            const int r = quad * 4 + reg;
#pragma unroll
            for (int ni = 0; ni < 2; ++ni) {
                const int col = n0 + ni * 16 + c;
                const unsigned ubits = (unsigned)(unsigned short)f2bf(accU[ni][reg]);
                const unsigned hbits = (unsigned)(unsigned short)hB[r][col];
                hu_t[(size_t)(e0 + r) * H_ + col] = (ubits << 16) | hbits;
            }
        }
    }
}

// root_vecs[b] = relu(eWo[root_wid[b]] + sum_nei @ Wo_bot)   (eWo includes bo)
__global__ __launch_bounds__(256) void k_root(
    const int* __restrict__ root_wid, const int* __restrict__ root_nei,
    const float* __restrict__ h, const float* __restrict__ eWo,
    const float* __restrict__ Wo, float* __restrict__ out)
{
    const int b = blockIdx.x, d = threadIdx.x;
    __shared__ float sn[H_];
    __shared__ int idx[NB_];
    if (d < NB_) idx[d] = root_nei[b * NB_ + d];
    __syncthreads();
    float s = 0.0f;
#pragma unroll
    for (int j = 0; j < NB_; ++j) s += h[(size_t)idx[j] * H_ + d];
    sn[d] = s;
    __syncthreads();
    float acc = eWo[(size_t)root_wid[b] * H_ + d];
    for (int k = 0; k < H_; ++k)
        acc = fmaf(sn[k], Wo[(size_t)(H_ + k) * H_ + d], acc);
    out[(size_t)b * H_ + d] = fmaxf(acc, 0.0f);
}

extern "C" void kernel_launch(void* const* d_in, const int* in_sizes, int n_in,
                              void* d_out, int out_size, void* d_ws, size_t ws_size,
                              hipStream_t stream)
{
    const int*   x_ids    = (const int*)d_in[0];
    const int*   nei_idx  = (const int*)d_in[1];
    const int*   root_wid = (const int*)d_in[2];
    const int*   root_nei = (const int*)d_in[3];
    const float* emb      = (const float*)d_in[4];
    const float* Wz       = (const float*)d_in[5];
    const float* bz       = (const float*)d_in[6];
    const float* Wr       = (const float*)d_in[7];
    const float* Ur       = (const float*)d_in[8];
    const float* bur      = (const float*)d_in[9];
    const float* Wh       = (const float*)d_in[10];
    const float* bh       = (const float*)d_in[11];
    const float* Wo       = (const float*)d_in[12];
    const float* bo       = (const float*)d_in[13];

    float* h        = (float*)d_out;                      // [(1+M), H]
    float* root_out = h + (size_t)(1 + M_) * H_;          // [B, H]

    unsigned* hu = (unsigned*)d_ws;                       // [(1+M), H] packed {h,u} bf16
    float* eWr  = (float*)(hu + (size_t)(1 + M_) * H_);   // [V, H] emb@Wr + bur
    float* eWz  = eWr  + (size_t)V_ * H_;                 // [V, H] emb@Wz_top + bz
    float* eWh  = eWz  + (size_t)V_ * H_;                 // [V, H] emb@Wh_top + bh
    float* eWo  = eWh  + (size_t)V_ * H_;                 // [V, H] emb@Wo_top + bo
    short* Wzt  = (short*)(eWo + (size_t)V_ * H_);        // [256,256] bf16 transposed
    short* Wht  = Wzt + 65536;
    short* Urt  = Wht + 65536;
    unsigned* eWzh = (unsigned*)(Urt + 65536);            // [V, H] packed {bf16(eWz), bf16(eWh)}

    k_wconv<<<dim3(769), dim3(256), 0, stream>>>(Wz, Wh, Ur, Wzt, Wht, Urt, h, hu);
    gemm_pre<<<dim3((V_ + 63) / 64, 4, 4), dim3(256), 0, stream>>>(
        emb, Wr, Wz, Wh, Wo, bur, bz, bh, bo, eWr, eWz, eWh, eWo);
    k_pack<<<dim3(V_ * H_ / 256), dim3(256), 0, stream>>>(eWz, eWh, eWzh);

    for (int t = 0; t < T_; ++t) {
        k_step<<<dim3(E_ / TM), dim3(512), 0, stream>>>(
            t, x_ids, nei_idx, h, hu, eWr, eWzh, Wzt, Wht, Urt,
            (t < T_ - 1) ? 1 : 0);
    }

    k_root<<<dim3(B_), dim3(256), 0, stream>>>(root_wid, root_nei, h, eWo, Wo, root_out);
}